// Round 3
// baseline (700.050 us; speedup 1.0000x reference)
//
#include <hip/hip_runtime.h>
#include <cstdint>
#include <cstddef>

// ---------------------------------------------------------------------------
// Mamba3Block on MI355X. B=2, L=4096, D_MODEL=1024, D_INNER=D_STATE=2048.
// R9: (a) XCD-balance fix — block-type partitions at granularity 8 (R8's
// even/odd split put all MFMA work on 4 of 8 XCDs: MfmaUtil 26%, occ 21%);
// (b) G3''+G45'' merged into ONE GEMM (same A=XC, same shape) via contiguous
// [WCBp;WXp] weight pair + mode-6 split store -> 9 dispatches;
// (c) column-major per-XCD tile mapping: each XCD owns gn/8 column panels
// (B-panel 1-2MB resident in its private L2), A streamed via L3.
// GEMM core: bf16 MFMA 16x16x32, 128x128 tile, BK=64, global_load_lds w16,
// XOR-swizzled LDS (conflicts = 0). Scans fp32, bf16 log-decay storage.
// ---------------------------------------------------------------------------

typedef unsigned short u16;                 // bf16 storage (bit pattern)
typedef __bf16 bf16x8 __attribute__((ext_vector_type(8)));
typedef float  f32x4  __attribute__((ext_vector_type(4)));

#define BDIM 256
#define M_ROWS 8192            // B*L
#define LSEQ   4096
#define DI     2048            // d_inner / d_state
#define NCH    64              // scan chunks
#define CLEN   64              // LSEQ / NCH

__device__ __forceinline__ float bf2f(u16 h) {
    return __uint_as_float(((unsigned int)h) << 16);
}
__device__ __forceinline__ u16 f2bf(float f) {
    unsigned int u = __float_as_uint(f);
    u = u + 0x7fffu + ((u >> 16) & 1u);     // RNE
    return (u16)(u >> 16);
}
__device__ __forceinline__ float siluf(float v) { return v / (1.0f + __expf(-v)); }

__device__ __forceinline__ void load16_to_lds(const u16* g, u16* l) {
    __builtin_amdgcn_global_load_lds((const __attribute__((address_space(1))) void*)g,
                                     (__attribute__((address_space(3))) void*)l,
                                     16, 0, 0);
}

// ---------------------------------------------------------------------------
// fused f32 -> bf16 convert of ALL inputs (1 launch), incl. +I diag segments,
// plus tail segment: NA[d] = -exp(A_log[d]) (f32, 2048 elems).
// ---------------------------------------------------------------------------
__global__ void k_cvt_all(const float* __restrict__ hs, const float* __restrict__ inproj,
                          const float* __restrict__ Bw, const float* __restrict__ Cw,
                          const float* __restrict__ outw, const float* __restrict__ delta,
                          const float* __restrict__ dtw, const float* __restrict__ Areal,
                          const float* __restrict__ Dw, const float* __restrict__ Alog,
                          u16* __restrict__ XH, u16* __restrict__ W1, u16* __restrict__ WBb,
                          u16* __restrict__ WC, u16* __restrict__ WO, u16* __restrict__ DLT,
                          u16* __restrict__ WDT, u16* __restrict__ Pb, u16* __restrict__ Db,
                          float* __restrict__ NA) {
    long i = (long)(blockIdx.x * BDIM + threadIdx.x) * 4;
    if (i >= 32112640L) {                       // NA tail: 2048 f32
        long j = i - 32112640L;
        if (j < 2048) {
            float4 v = *reinterpret_cast<const float4*>(Alog + j);
            float4 o = {-__expf(v.x), -__expf(v.y), -__expf(v.z), -__expf(v.w)};
            *reinterpret_cast<float4*>(NA + j) = o;
        }
        return;
    }
    const float* src; u16* dst; long off; bool diag = false;
    if      (i <  8388608L) { src = hs;     dst = XH;  off = 0L; }
    else if (i < 12582912L) { src = inproj; dst = W1;  off = 8388608L; }
    else if (i < 16777216L) { src = Bw;     dst = WBb; off = 12582912L; }
    else if (i < 20971520L) { src = Cw;     dst = WC;  off = 16777216L; }
    else if (i < 23068672L) { src = outw;   dst = WO;  off = 20971520L; }
    else if (i < 23592960L) { src = delta;  dst = DLT; off = 23068672L; }
    else if (i < 23724032L) { src = dtw;    dst = WDT; off = 23592960L; }
    else if (i < 27918336L) { src = Areal;  dst = Pb;  off = 23724032L; diag = true; }
    else                    { src = Dw;     dst = Db;  off = 27918336L; diag = true; }
    long j = i - off;
    float4 v = *reinterpret_cast<const float4*>(src + j);
    if (diag) {
        int r = (int)(j >> 11), c = (int)(j & 2047);
        if (r >= c && r < c + 4) (&v.x)[r - c] += 1.0f;
    }
    ushort2 a = {f2bf(v.x), f2bf(v.y)};
    ushort2 b = {f2bf(v.z), f2bf(v.w)};
    *reinterpret_cast<ushort2*>(dst + j)     = a;
    *reinterpret_cast<ushort2*>(dst + j + 2) = b;
}

// ---------------------------------------------------------------------------
// GEMM tile core: C_tile = A1*W1^T (+ A2*W2^T), bf16 in, f32 acc.
// LDS XOR-swizzle (r,c) -> r*64 + (c ^ ((r&7)*8)); staging = global_load_lds.
// mode 0: store bf16[N-stride]; 2: store f32; 5: log-decay bf16 (bias2 = NA,
// premultiplied -exp(Alog), fast softplus); 6: split store; 8: transposed store
// ---------------------------------------------------------------------------
__device__ __forceinline__ void gemm_core(
    u16* As, u16* Bs,
    const u16* __restrict__ A1, const u16* __restrict__ W1, int K1,
    const u16* __restrict__ A2, const u16* __restrict__ W2, int K2,
    int N, float* __restrict__ outf, u16* __restrict__ outb, u16* __restrict__ outb2,
    const float* __restrict__ bias1, const float* __restrict__ bias2,
    int m0, int n0, int mode) {
    const int tid  = threadIdx.x;
    const int wave = tid >> 6;
    const int lane = tid & 63;
    const int wm = (wave >> 1) * 64;
    const int wn = (wave & 1) * 64;
    const int lr = lane & 15;
    const int lq = lane >> 4;
    const int stg_row = lane >> 3;
    const int stg_col = (((lane & 7) ^ (lane >> 3)) << 3);

    f32x4 acc[4][4] = {};

    const int nt1 = K1 >> 6;
    const int nt2 = K2 >> 6;
    const int ntot = nt1 + nt2;

    for (int kt = 0; kt < ntot; ++kt) {
        const u16* Ap; const u16* Wp; int ld, k0;
        if (kt < nt1) { Ap = A1; Wp = W1; ld = K1; k0 = kt << 6; }
        else          { Ap = A2; Wp = W2; ld = K2; k0 = (kt - nt1) << 6; }
        #pragma unroll
        for (int i = 0; i < 4; ++i) {
            int chunk = wave * 4 + i;                 // wave-uniform
            int r = chunk * 8 + stg_row;
            load16_to_lds(Ap + (size_t)(m0 + r) * ld + (k0 + stg_col), As + chunk * 512);
            load16_to_lds(Wp + (size_t)(n0 + r) * ld + (k0 + stg_col), Bs + chunk * 512);
        }
        __syncthreads();
        #pragma unroll
        for (int kk = 0; kk < 64; kk += 32) {
            bf16x8 af[4], bfr[4];
            #pragma unroll
            for (int i = 0; i < 4; ++i) {
                int R = wm + i * 16 + lr;
                af[i] = *reinterpret_cast<const bf16x8*>(
                    &As[R * 64 + ((kk + lq * 8) ^ ((R & 7) << 3))]);
            }
            #pragma unroll
            for (int i = 0; i < 4; ++i) {
                int R = wn + i * 16 + lr;
                bfr[i] = *reinterpret_cast<const bf16x8*>(
                    &Bs[R * 64 + ((kk + lq * 8) ^ ((R & 7) << 3))]);
            }
            #pragma unroll
            for (int mi = 0; mi < 4; ++mi)
                #pragma unroll
                for (int ni = 0; ni < 4; ++ni)
                    acc[mi][ni] = __builtin_amdgcn_mfma_f32_16x16x32_bf16(
                        af[mi], bfr[ni], acc[mi][ni], 0, 0, 0);
        }
        __syncthreads();
    }

    if (mode == 8) {                      // transposed store (square 2048 out)
        #pragma unroll
        for (int mi = 0; mi < 4; ++mi) {
            #pragma unroll
            for (int ni = 0; ni < 4; ++ni) {
                int row = m0 + wm + mi * 16 + lq * 4;
                int col = n0 + wn + ni * 16 + lr;
                ushort4 v;
                v.x = f2bf(acc[mi][ni][0]); v.y = f2bf(acc[mi][ni][1]);
                v.z = f2bf(acc[mi][ni][2]); v.w = f2bf(acc[mi][ni][3]);
                *reinterpret_cast<ushort4*>(outb + (size_t)col * 2048 + row) = v;
            }
        }
        return;
    }

    #pragma unroll
    for (int mi = 0; mi < 4; ++mi) {
        #pragma unroll
        for (int ni = 0; ni < 4; ++ni) {
            #pragma unroll
            for (int j = 0; j < 4; ++j) {
                int row = m0 + wm + mi * 16 + lq * 4 + j;
                int col = n0 + wn + ni * 16 + lr;
                float v = acc[mi][ni][j];
                if (mode == 6) {
                    if (col < 2048) outb [(size_t)row * 2048 + col]        = f2bf(v);
                    else            outb2[(size_t)row * 2048 + col - 2048] = f2bf(v);
                } else if (mode == 5) {
                    float dlt = v + bias1[col];
                    float sp  = (dlt > 15.f) ? dlt : __logf(1.f + __expf(dlt));
                    outb[(size_t)row * N + col] = f2bf(bias2[col] * sp);
                } else if (mode == 2) {
                    outf[(size_t)row * N + col] = v;
                } else {
                    outb[(size_t)row * N + col] = f2bf(v);
                }
            }
        }
    }
}

// Column-major per-XCD tile map: XCD (q&7) owns gn/8 col-panels; within an
// XCD, tiles walk down rows (gm per column) so its B-panels stay L2-resident.
__device__ __forceinline__ void tile_coords(int q, int gm, int gn, int& m0, int& n0) {
    int xcd = q & 7;
    int loc = q >> 3;
    int cl  = loc / gm;
    int r   = loc - cl * gm;
    m0 = r * 128;
    n0 = (xcd * (gn >> 3) + cl) * 128;
}

// batch1: [0,256) pre1' PBt = Pb@WBb^T = P@B^T | [256,512) pre2 WXp=Db@Pb^T |
//         [512,2560) G1 split: XZ = XH @ W1^T (N=4096) -> XB / ZB
__global__ __launch_bounds__(256, 4)
void k_batch1(const u16* __restrict__ XH, const u16* __restrict__ W1,
              const u16* __restrict__ WBb, const u16* __restrict__ Pb,
              const u16* __restrict__ Db,
              u16* __restrict__ PBt, u16* __restrict__ WXp,
              u16* __restrict__ XB, u16* __restrict__ ZB) {
    __shared__ u16 As[128 * 64];
    __shared__ u16 Bs[128 * 64];
    int bid = blockIdx.x;
    int m0, n0;
    if (bid < 256) {
        tile_coords(bid, 16, 16, m0, n0);
        gemm_core(As, Bs, Pb, WBb, DI, nullptr, nullptr, 0, DI,
                  nullptr, PBt, nullptr, nullptr, nullptr, m0, n0, 0);
    } else if (bid < 512) {
        tile_coords(bid - 256, 16, 16, m0, n0);
        gemm_core(As, Bs, Db, Pb, DI, nullptr, nullptr, 0, DI,
                  nullptr, WXp, nullptr, nullptr, nullptr, m0, n0, 0);
    } else {
        tile_coords(bid - 512, 64, 32, m0, n0);
        gemm_core(As, Bs, XH, W1, 1024, nullptr, nullptr, 0, 4096,
                  nullptr, XB, ZB, nullptr, nullptr, m0, n0, 6);
    }
}

// conv+pre3: [0,256) pre3 WCBp = (PBt@WC^T)^T = C·B·P^T (mode 8) |
//            [256,...) depthwise causal conv (k=4) + bias + SiLU
__global__ __launch_bounds__(256, 4)
void k_conv_pre3(const u16* __restrict__ x, const float* __restrict__ w,
                 const float* __restrict__ b, u16* __restrict__ out,
                 const u16* __restrict__ PBt, const u16* __restrict__ WC,
                 u16* __restrict__ WCBp) {
    __shared__ u16 As[128 * 64];
    __shared__ u16 Bs[128 * 64];
    if (blockIdx.x < 256) {
        int m0, n0;
        tile_coords(blockIdx.x, 16, 16, m0, n0);
        gemm_core(As, Bs, PBt, WC, DI, nullptr, nullptr, 0, DI,
                  nullptr, WCBp, nullptr, nullptr, nullptr, m0, n0, 8);
        return;
    }
    int idx = (blockIdx.x - 256) * BDIM + threadIdx.x;   // over M_ROWS*DI
    int d  = idx & (DI - 1);
    int bl = idx >> 11;
    int l  = bl & (LSEQ - 1);
    float4 wv = *reinterpret_cast<const float4*>(w + d * 4);
    float wj[4] = {wv.x, wv.y, wv.z, wv.w};
    float acc = b[d];
    #pragma unroll
    for (int j = 0; j < 4; ++j) {
        int ll = l - 3 + j;
        if (ll >= 0) acc += wj[j] * bf2f(x[(size_t)(bl - 3 + j) * DI + d]);
    }
    out[idx] = f2bf(siluf(acc));
}

// batch36: merged G36 (2048 tiles) + G6 (1024 tiles), interleaved in groups
// of 8 blocks (pattern G36,G36,G6 repeating) so BOTH types cover all 8 XCDs
// and G6's VALU/store hides under G36's MFMA.
//  G36: [BXC | X3g] = XC @ [WCBp ; WXp]^T   (N=4096, mode-6 split store)
//  G6 : LD = logdecay(DLT@WDT^T)            (mode 5)
__global__ __launch_bounds__(256, 4)
void k_batch36(const u16* __restrict__ XC, const u16* __restrict__ WCB2,
               const u16* __restrict__ DLT, const u16* __restrict__ WDT,
               const float* __restrict__ dtb, const float* __restrict__ NA,
               u16* __restrict__ BXC, u16* __restrict__ X3, u16* __restrict__ LD) {
    __shared__ u16 As[128 * 64];
    __shared__ u16 Bs[128 * 64];
    int bid = blockIdx.x;
    int g   = bid >> 3;
    int l8  = bid & 7;
    int t3  = g % 3;                       // 0,1 -> G36 ; 2 -> G6
    int m0, n0;
    if (t3 < 2) {
        int q = ((g / 3) * 2 + t3) * 8 + l8;          // [0,2048)
        tile_coords(q, 64, 32, m0, n0);
        gemm_core(As, Bs, XC, WCB2, DI, nullptr, nullptr, 0, 4096,
                  nullptr, BXC, X3, nullptr, nullptr, m0, n0, 6);
    } else {
        int q = (g / 3) * 8 + l8;                     // [0,1024)
        tile_coords(q, 64, 16, m0, n0);
        gemm_core(As, Bs, DLT, WDT, 64, nullptr, nullptr, 0, DI,
                  nullptr, LD, nullptr, dtb, NA, m0, n0, 5);
    }
}

// single GEMM wrapper (G7): grid dim3(gn, gm)
template <int MODE>
__global__ __launch_bounds__(256, 4)
void k_gemm(const u16* __restrict__ A1, const u16* __restrict__ W1, int K1,
            const u16* __restrict__ A2, const u16* __restrict__ W2, int K2,
            int N, float* __restrict__ outf, u16* __restrict__ outb) {
    __shared__ u16 As[128 * 64];
    __shared__ u16 Bs[128 * 64];
    int bid = blockIdx.x + gridDim.x * blockIdx.y;
    int m0, n0;
    tile_coords(bid, gridDim.y, gridDim.x, m0, n0);
    gemm_core(As, Bs, A1, W1, K1, A2, W2, K2, N,
              outf, outb, nullptr, nullptr, nullptr, m0, n0, MODE);
}

// ---------------------------------------------------------------------------
// cumsum over l (chunked): BXC bf16 -> (p1) chunk sums; (p23) folds carries,
// adds X3g in place: X3 = cumsum(BXC) + X3g
// thread layout: t = ((b*NCH + c)*DI + s); NCH*DI = 2^17
// ---------------------------------------------------------------------------
__global__ void k_cumsum_p1(const u16* __restrict__ Bx, float* __restrict__ aux) {
    int t = blockIdx.x * BDIM + threadIdx.x;
    int s = t & (DI - 1);
    int c = (t >> 11) & (NCH - 1);
    int b = t >> 17;
    const u16* p = Bx + ((size_t)(b * LSEQ + c * CLEN) * DI) + s;
    float sum = 0.f;
    for (int i = 0; i < CLEN; ++i) sum += bf2f(p[(size_t)i * DI]);
    aux[t] = sum;
}
__global__ void k_cumsum_p23(const u16* __restrict__ Bx, const float* __restrict__ aux,
                             u16* x3) {                 // read X3g, write X3 in place
    int t = blockIdx.x * BDIM + threadIdx.x;
    int s = t & (DI - 1);
    int c = (t >> 11) & (NCH - 1);
    int b = t >> 17;
    float run = 0.f;
    for (int j = 0; j < c; ++j) run += aux[(b * NCH + j) * DI + s];   // fold p2
    size_t base = ((size_t)(b * LSEQ + c * CLEN) * DI) + s;
    for (int i = 0; i < CLEN; ++i) {
        size_t ix = base + (size_t)i * DI;
        run += bf2f(Bx[ix]);
        x3[ix] = f2bf(run + bf2f(x3[ix]));
    }
}

// ---------------------------------------------------------------------------
// selective scan (2-kernel): s_l = a_l * s_{l-1} + u_l with a = exp(logdec)
// p23 fuses carry fold + x4 = s + u*D_ss ; out = x4 * silu(z)
// ---------------------------------------------------------------------------
__global__ void k_scan_p1(const u16* __restrict__ ld_, const u16* __restrict__ u,
                          float* __restrict__ auxA, float* __restrict__ auxS) {
    int t = blockIdx.x * BDIM + threadIdx.x;
    int d = t & (DI - 1);
    int c = (t >> 11) & (NCH - 1);
    int b = t >> 17;
    size_t base = ((size_t)(b * LSEQ + c * CLEN) * DI) + d;
    float ap = 1.f, s = 0.f;
    for (int i = 0; i < CLEN; ++i) {
        size_t ix = base + (size_t)i * DI;
        float a = __expf(bf2f(ld_[ix]));
        s = fmaf(a, s, bf2f(u[ix]));
        ap *= a;
    }
    auxA[t] = ap; auxS[t] = s;
}
__global__ void k_scan_p23(const u16* __restrict__ ld_, const u16* __restrict__ u,
                           const float* __restrict__ auxA, const float* __restrict__ auxS,
                           const u16* __restrict__ z, const float* __restrict__ Dss,
                           u16* __restrict__ outb) {
    int t = blockIdx.x * BDIM + threadIdx.x;
    int d = t & (DI - 1);
    int c = (t >> 11) & (NCH - 1);
    int b = t >> 17;
    float s = 0.f;
    for (int j = 0; j < c; ++j) {                                    // fold p2
        int i = (b * NCH + j) * DI + d;
        s = fmaf(auxA[i], s, auxS[i]);
    }
    size_t base = ((size_t)(b * LSEQ + c * CLEN) * DI) + d;
    float dss = Dss[d];
    for (int i = 0; i < CLEN; ++i) {
        size_t ix = base + (size_t)i * DI;
        float a = __expf(bf2f(ld_[ix]));
        float uu = bf2f(u[ix]);
        s = fmaf(a, s, uu);
        float x4 = s + uu * dss;
        float zz = bf2f(z[ix]);
        outb[ix] = f2bf(x4 * siluf(zz));
    }
}

// ---------------------------------------------------------------------------
extern "C" void kernel_launch(void* const* d_in, const int* in_sizes, int n_in,
                              void* d_out, int out_size, void* d_ws, size_t ws_size,
                              hipStream_t stream) {
    const float* hs     = (const float*)d_in[0];
    const float* delta  = (const float*)d_in[1];
    const float* inproj = (const float*)d_in[2];
    const float* convw  = (const float*)d_in[3];
    const float* convb  = (const float*)d_in[4];
    const float* Areal  = (const float*)d_in[5];
    const float* Bw     = (const float*)d_in[6];
    const float* Cw     = (const float*)d_in[7];
    const float* Dw     = (const float*)d_in[8];
    const float* dtw    = (const float*)d_in[9];
    const float* dtb    = (const float*)d_in[10];
    const float* Alog   = (const float*)d_in[11];
    const float* Dss    = (const float*)d_in[12];
    const float* outw   = (const float*)d_in[13];
    float* out = (float*)d_out;

    // ---- liveness-overlaid workspace layout (~241 MB total) ----
    const size_t SZ_ACT = (size_t)M_ROWS * DI * 2;     // 32 MB
    char* p = (char*)d_ws;
    u16* ZB  = (u16*)p; p += SZ_ACT;                   // z: batch1 -> scan_p23
    u16* XB  = (u16*)p;                                // x: batch1 -> conv
    u16* X3  = XB;      p += SZ_ACT;                   // X3g: batch36 -> cumsum_p23 (in place) -> scans
    u16* XC  = (u16*)p;                                // conv out -> batch36
    u16* OUT = XC;      p += SZ_ACT;                   // scan_p23 out -> G7
    u16* BXC = (u16*)p; p += SZ_ACT;                   // batch36 out -> cumsum
    u16* WCBp= (u16*)p;                                // C·B·P^T (8MB)
    u16* WXp = WCBp + (size_t)DI * DI;                 // (I+D_w)@P^T, CONTIGUOUS after WCBp
                        p += SZ_ACT;                   // 32MB slot holds both (16MB used)
    u16* XH  = (u16*)p;                                // hs bf16 (dead after batch1)
    u16* LD  = XH;                                     // log-decay overlays XH+W1+WBb (32MB)
                        p += (size_t)M_ROWS * 1024 * 2;   // 16 MB
    u16* W1  = (u16*)p; p += (size_t)4096 * 1024 * 2;     // 8 MB
    u16* WBb = (u16*)p; p += (size_t)DI * DI * 2;         // 8 MB  bf16(B_w)
    u16* WC  = (u16*)p; p += (size_t)DI * DI * 2;         // 8 MB  bf16(C_w)
    u16* Pb  = (u16*)p; p += (size_t)DI * DI * 2;         // 8 MB  bf16(I+A_real)
    u16* Db  = (u16*)p; p += (size_t)DI * DI * 2;         // 8 MB  bf16(I+D_w)
    u16* PBt = (u16*)p; p += (size_t)DI * DI * 2;         // 8 MB  P @ B^T
    p += (size_t)DI * DI * 2;                             // (old WXp slot, unused)
    u16* WO  = (u16*)p; p += (size_t)1024 * DI * 2;       // 4 MB
    u16* WDT = (u16*)p; p += (size_t)DI * 64 * 2;
    u16* DLT = (u16*)p; p += (size_t)M_ROWS * 64 * 2;
    float* aux1 = (float*)p; p += (size_t)2 * NCH * DI * 4;   // 1 MB
    float* auxA = (float*)p; p += (size_t)2 * NCH * DI * 4;
    float* auxS = (float*)p; p += (size_t)2 * NCH * DI * 4;
    float* NA   = (float*)p; p += (size_t)DI * 4;             // -exp(A_log)

    // 1) all converts (incl. +I for Pb/Db, NA tail)
    k_cvt_all<<<31362, BDIM, 0, stream>>>(hs, inproj, Bw, Cw, outw, delta, dtw,
                                          Areal, Dw, Alog,
                                          XH, W1, WBb, WC, WO, DLT, WDT, Pb, Db, NA);
    // 2) pre1' (PBt) + pre2 (WXp) + G1(split)
    k_batch1<<<2560, BDIM, 0, stream>>>(XH, W1, WBb, Pb, Db, PBt, WXp, XB, ZB);
    // 3) pre3 (WCBp, 256 blocks) + conv + SiLU
    k_conv_pre3<<<256 + (M_ROWS * DI) / BDIM, BDIM, 0, stream>>>(
        XB, convw, convb, XC, PBt, WC, WCBp);
    // 4) G36 ([BXC|X3g] = XC@[WCBp;WXp]^T) + G6 (LD), group-of-8 interleave
    k_batch36<<<3072, BDIM, 0, stream>>>(XC, WCBp, DLT, WDT, dtb, NA, BXC, X3, LD);
    // 5) cumsum chunk sums
    k_cumsum_p1<<<(2 * NCH * DI) / BDIM, BDIM, 0, stream>>>(BXC, aux1);
    // 6) cumsum fold + add: X3 = cumsum(BXC) + X3g   (in place)
    k_cumsum_p23<<<(2 * NCH * DI) / BDIM, BDIM, 0, stream>>>(BXC, aux1, X3);
    // 7-8) selective scan + epilogue -> OUT (overlays dead XC)
    k_scan_p1<<<(2 * NCH * DI) / BDIM, BDIM, 0, stream>>>(LD, X3, auxA, auxS);
    k_scan_p23<<<(2 * NCH * DI) / BDIM, BDIM, 0, stream>>>(LD, X3, auxA, auxS,
                                                           ZB, Dss, OUT);
    // 9) G7: out = OUT @ out_proj^T (f32)
    k_gemm<2><<<dim3(8, 64), BDIM, 0, stream>>>(OUT, WO, DI, nullptr, nullptr, 0,
                                                1024, out, nullptr);
}

// Round 4
// 697.027 us; speedup vs baseline: 1.0043x; 1.0043x over previous
//
#include <hip/hip_runtime.h>
#include <cstdint>
#include <cstddef>

// ---------------------------------------------------------------------------
// Mamba3Block on MI355X. B=2, L=4096, D_MODEL=1024, D_INNER=D_STATE=2048.
// R10: revert tile map to R6's M-stripe-per-XCD (R9's column-major map
// streamed full A per column panel: batch36 FETCH 546MB, MfmaUtil 33%,
// batch1 regressed). Per-XCD: A-stripe 4MB L2-resident, B streamed via L3.
// Kept from R9: G3''+G45'' merged into one N=4096 GEMM (mode-6 split store),
// group-of-8 XCD-balanced G36/G6 interleave, 9 dispatches.
// Kept from R7/R8: cumsum commutes with C-projection (ST GEMM deleted);
// fast softplus + NA = -exp(A_log) precompute.
// GEMM core: bf16 MFMA 16x16x32, 128x128 tile, BK=64, global_load_lds w16,
// XOR-swizzled LDS (conflicts = 0). Scans fp32, bf16 log-decay storage.
// ---------------------------------------------------------------------------

typedef unsigned short u16;                 // bf16 storage (bit pattern)
typedef __bf16 bf16x8 __attribute__((ext_vector_type(8)));
typedef float  f32x4  __attribute__((ext_vector_type(4)));

#define BDIM 256
#define M_ROWS 8192            // B*L
#define LSEQ   4096
#define DI     2048            // d_inner / d_state
#define NCH    64              // scan chunks
#define CLEN   64              // LSEQ / NCH

__device__ __forceinline__ float bf2f(u16 h) {
    return __uint_as_float(((unsigned int)h) << 16);
}
__device__ __forceinline__ u16 f2bf(float f) {
    unsigned int u = __float_as_uint(f);
    u = u + 0x7fffu + ((u >> 16) & 1u);     // RNE
    return (u16)(u >> 16);
}
__device__ __forceinline__ float siluf(float v) { return v / (1.0f + __expf(-v)); }

__device__ __forceinline__ void load16_to_lds(const u16* g, u16* l) {
    __builtin_amdgcn_global_load_lds((const __attribute__((address_space(1))) void*)g,
                                     (__attribute__((address_space(3))) void*)l,
                                     16, 0, 0);
}

// ---------------------------------------------------------------------------
// fused f32 -> bf16 convert of ALL inputs (1 launch), incl. +I diag segments,
// plus tail segment: NA[d] = -exp(A_log[d]) (f32, 2048 elems).
// ---------------------------------------------------------------------------
__global__ void k_cvt_all(const float* __restrict__ hs, const float* __restrict__ inproj,
                          const float* __restrict__ Bw, const float* __restrict__ Cw,
                          const float* __restrict__ outw, const float* __restrict__ delta,
                          const float* __restrict__ dtw, const float* __restrict__ Areal,
                          const float* __restrict__ Dw, const float* __restrict__ Alog,
                          u16* __restrict__ XH, u16* __restrict__ W1, u16* __restrict__ WBb,
                          u16* __restrict__ WC, u16* __restrict__ WO, u16* __restrict__ DLT,
                          u16* __restrict__ WDT, u16* __restrict__ Pb, u16* __restrict__ Db,
                          float* __restrict__ NA) {
    long i = (long)(blockIdx.x * BDIM + threadIdx.x) * 4;
    if (i >= 32112640L) {                       // NA tail: 2048 f32
        long j = i - 32112640L;
        if (j < 2048) {
            float4 v = *reinterpret_cast<const float4*>(Alog + j);
            float4 o = {-__expf(v.x), -__expf(v.y), -__expf(v.z), -__expf(v.w)};
            *reinterpret_cast<float4*>(NA + j) = o;
        }
        return;
    }
    const float* src; u16* dst; long off; bool diag = false;
    if      (i <  8388608L) { src = hs;     dst = XH;  off = 0L; }
    else if (i < 12582912L) { src = inproj; dst = W1;  off = 8388608L; }
    else if (i < 16777216L) { src = Bw;     dst = WBb; off = 12582912L; }
    else if (i < 20971520L) { src = Cw;     dst = WC;  off = 16777216L; }
    else if (i < 23068672L) { src = outw;   dst = WO;  off = 20971520L; }
    else if (i < 23592960L) { src = delta;  dst = DLT; off = 23068672L; }
    else if (i < 23724032L) { src = dtw;    dst = WDT; off = 23592960L; }
    else if (i < 27918336L) { src = Areal;  dst = Pb;  off = 23724032L; diag = true; }
    else                    { src = Dw;     dst = Db;  off = 27918336L; diag = true; }
    long j = i - off;
    float4 v = *reinterpret_cast<const float4*>(src + j);
    if (diag) {
        int r = (int)(j >> 11), c = (int)(j & 2047);
        if (r >= c && r < c + 4) (&v.x)[r - c] += 1.0f;
    }
    ushort2 a = {f2bf(v.x), f2bf(v.y)};
    ushort2 b = {f2bf(v.z), f2bf(v.w)};
    *reinterpret_cast<ushort2*>(dst + j)     = a;
    *reinterpret_cast<ushort2*>(dst + j + 2) = b;
}

// ---------------------------------------------------------------------------
// GEMM tile core: C_tile = A1*W1^T (+ A2*W2^T), bf16 in, f32 acc.
// LDS XOR-swizzle (r,c) -> r*64 + (c ^ ((r&7)*8)); staging = global_load_lds.
// mode 0: store bf16[N-stride]; 2: store f32; 5: log-decay bf16 (bias2 = NA,
// premultiplied -exp(Alog), fast softplus); 6: split store; 8: transposed store
// ---------------------------------------------------------------------------
__device__ __forceinline__ void gemm_core(
    u16* As, u16* Bs,
    const u16* __restrict__ A1, const u16* __restrict__ W1, int K1,
    const u16* __restrict__ A2, const u16* __restrict__ W2, int K2,
    int N, float* __restrict__ outf, u16* __restrict__ outb, u16* __restrict__ outb2,
    const float* __restrict__ bias1, const float* __restrict__ bias2,
    int m0, int n0, int mode) {
    const int tid  = threadIdx.x;
    const int wave = tid >> 6;
    const int lane = tid & 63;
    const int wm = (wave >> 1) * 64;
    const int wn = (wave & 1) * 64;
    const int lr = lane & 15;
    const int lq = lane >> 4;
    const int stg_row = lane >> 3;
    const int stg_col = (((lane & 7) ^ (lane >> 3)) << 3);

    f32x4 acc[4][4] = {};

    const int nt1 = K1 >> 6;
    const int nt2 = K2 >> 6;
    const int ntot = nt1 + nt2;

    for (int kt = 0; kt < ntot; ++kt) {
        const u16* Ap; const u16* Wp; int ld, k0;
        if (kt < nt1) { Ap = A1; Wp = W1; ld = K1; k0 = kt << 6; }
        else          { Ap = A2; Wp = W2; ld = K2; k0 = (kt - nt1) << 6; }
        #pragma unroll
        for (int i = 0; i < 4; ++i) {
            int chunk = wave * 4 + i;                 // wave-uniform
            int r = chunk * 8 + stg_row;
            load16_to_lds(Ap + (size_t)(m0 + r) * ld + (k0 + stg_col), As + chunk * 512);
            load16_to_lds(Wp + (size_t)(n0 + r) * ld + (k0 + stg_col), Bs + chunk * 512);
        }
        __syncthreads();
        #pragma unroll
        for (int kk = 0; kk < 64; kk += 32) {
            bf16x8 af[4], bfr[4];
            #pragma unroll
            for (int i = 0; i < 4; ++i) {
                int R = wm + i * 16 + lr;
                af[i] = *reinterpret_cast<const bf16x8*>(
                    &As[R * 64 + ((kk + lq * 8) ^ ((R & 7) << 3))]);
            }
            #pragma unroll
            for (int i = 0; i < 4; ++i) {
                int R = wn + i * 16 + lr;
                bfr[i] = *reinterpret_cast<const bf16x8*>(
                    &Bs[R * 64 + ((kk + lq * 8) ^ ((R & 7) << 3))]);
            }
            #pragma unroll
            for (int mi = 0; mi < 4; ++mi)
                #pragma unroll
                for (int ni = 0; ni < 4; ++ni)
                    acc[mi][ni] = __builtin_amdgcn_mfma_f32_16x16x32_bf16(
                        af[mi], bfr[ni], acc[mi][ni], 0, 0, 0);
        }
        __syncthreads();
    }

    if (mode == 8) {                      // transposed store (square 2048 out)
        #pragma unroll
        for (int mi = 0; mi < 4; ++mi) {
            #pragma unroll
            for (int ni = 0; ni < 4; ++ni) {
                int row = m0 + wm + mi * 16 + lq * 4;
                int col = n0 + wn + ni * 16 + lr;
                ushort4 v;
                v.x = f2bf(acc[mi][ni][0]); v.y = f2bf(acc[mi][ni][1]);
                v.z = f2bf(acc[mi][ni][2]); v.w = f2bf(acc[mi][ni][3]);
                *reinterpret_cast<ushort4*>(outb + (size_t)col * 2048 + row) = v;
            }
        }
        return;
    }

    #pragma unroll
    for (int mi = 0; mi < 4; ++mi) {
        #pragma unroll
        for (int ni = 0; ni < 4; ++ni) {
            #pragma unroll
            for (int j = 0; j < 4; ++j) {
                int row = m0 + wm + mi * 16 + lq * 4 + j;
                int col = n0 + wn + ni * 16 + lr;
                float v = acc[mi][ni][j];
                if (mode == 6) {
                    if (col < 2048) outb [(size_t)row * 2048 + col]        = f2bf(v);
                    else            outb2[(size_t)row * 2048 + col - 2048] = f2bf(v);
                } else if (mode == 5) {
                    float dlt = v + bias1[col];
                    float sp  = (dlt > 15.f) ? dlt : __logf(1.f + __expf(dlt));
                    outb[(size_t)row * N + col] = f2bf(bias2[col] * sp);
                } else if (mode == 2) {
                    outf[(size_t)row * N + col] = v;
                } else {
                    outb[(size_t)row * N + col] = f2bf(v);
                }
            }
        }
    }
}

// M-stripe-per-XCD tile map (R6 form): XCD (q&7) owns a contiguous range of
// tile-ids = an M-stripe of 8 m-tiles x all n. A-stripe (<=4MB) stays
// L2-resident per XCD; B streamed once per XCD via L3.
__device__ __forceinline__ void tile_coords(int q, int T, int gn, int& m0, int& n0) {
    int nloc = T >> 3;
    int nid  = (q & 7) * nloc + (q >> 3);
    m0 = (nid / gn) * 128;
    n0 = (nid % gn) * 128;
}

// batch1: [0,256) pre1' PBt = Pb@WBb^T = P@B^T | [256,512) pre2 WXp=Db@Pb^T |
//         [512,2560) G1 split: XZ = XH @ W1^T (N=4096) -> XB / ZB
__global__ __launch_bounds__(256, 4)
void k_batch1(const u16* __restrict__ XH, const u16* __restrict__ W1,
              const u16* __restrict__ WBb, const u16* __restrict__ Pb,
              const u16* __restrict__ Db,
              u16* __restrict__ PBt, u16* __restrict__ WXp,
              u16* __restrict__ XB, u16* __restrict__ ZB) {
    __shared__ u16 As[128 * 64];
    __shared__ u16 Bs[128 * 64];
    int bid = blockIdx.x;
    int m0, n0;
    if (bid < 256) {
        tile_coords(bid, 256, 16, m0, n0);
        gemm_core(As, Bs, Pb, WBb, DI, nullptr, nullptr, 0, DI,
                  nullptr, PBt, nullptr, nullptr, nullptr, m0, n0, 0);
    } else if (bid < 512) {
        tile_coords(bid - 256, 256, 16, m0, n0);
        gemm_core(As, Bs, Db, Pb, DI, nullptr, nullptr, 0, DI,
                  nullptr, WXp, nullptr, nullptr, nullptr, m0, n0, 0);
    } else {
        tile_coords(bid - 512, 2048, 32, m0, n0);
        gemm_core(As, Bs, XH, W1, 1024, nullptr, nullptr, 0, 4096,
                  nullptr, XB, ZB, nullptr, nullptr, m0, n0, 6);
    }
}

// conv+pre3: [0,256) pre3 WCBp = (PBt@WC^T)^T = C·B·P^T (mode 8) |
//            [256,...) depthwise causal conv (k=4) + bias + SiLU
__global__ __launch_bounds__(256, 4)
void k_conv_pre3(const u16* __restrict__ x, const float* __restrict__ w,
                 const float* __restrict__ b, u16* __restrict__ out,
                 const u16* __restrict__ PBt, const u16* __restrict__ WC,
                 u16* __restrict__ WCBp) {
    __shared__ u16 As[128 * 64];
    __shared__ u16 Bs[128 * 64];
    if (blockIdx.x < 256) {
        int m0, n0;
        tile_coords(blockIdx.x, 256, 16, m0, n0);
        gemm_core(As, Bs, PBt, WC, DI, nullptr, nullptr, 0, DI,
                  nullptr, WCBp, nullptr, nullptr, nullptr, m0, n0, 8);
        return;
    }
    int idx = (blockIdx.x - 256) * BDIM + threadIdx.x;   // over M_ROWS*DI
    int d  = idx & (DI - 1);
    int bl = idx >> 11;
    int l  = bl & (LSEQ - 1);
    float4 wv = *reinterpret_cast<const float4*>(w + d * 4);
    float wj[4] = {wv.x, wv.y, wv.z, wv.w};
    float acc = b[d];
    #pragma unroll
    for (int j = 0; j < 4; ++j) {
        int ll = l - 3 + j;
        if (ll >= 0) acc += wj[j] * bf2f(x[(size_t)(bl - 3 + j) * DI + d]);
    }
    out[idx] = f2bf(siluf(acc));
}

// batch36: merged G36 (2048 tiles) + G6 (1024 tiles), interleaved in groups
// of 8 blocks (pattern G36,G36,G6 repeating) so BOTH types cover all 8 XCDs
// and G6's VALU/store hides under G36's MFMA.
//  G36: [BXC | X3g] = XC @ [WCBp ; WXp]^T   (N=4096, mode-6 split store)
//  G6 : LD = logdecay(DLT@WDT^T)            (mode 5)
__global__ __launch_bounds__(256, 4)
void k_batch36(const u16* __restrict__ XC, const u16* __restrict__ WCB2,
               const u16* __restrict__ DLT, const u16* __restrict__ WDT,
               const float* __restrict__ dtb, const float* __restrict__ NA,
               u16* __restrict__ BXC, u16* __restrict__ X3, u16* __restrict__ LD) {
    __shared__ u16 As[128 * 64];
    __shared__ u16 Bs[128 * 64];
    int bid = blockIdx.x;
    int g   = bid >> 3;
    int l8  = bid & 7;
    int t3  = g % 3;                       // 0,1 -> G36 ; 2 -> G6
    int m0, n0;
    if (t3 < 2) {
        int q = ((g / 3) * 2 + t3) * 8 + l8;          // [0,2048)
        tile_coords(q, 2048, 32, m0, n0);
        gemm_core(As, Bs, XC, WCB2, DI, nullptr, nullptr, 0, 4096,
                  nullptr, BXC, X3, nullptr, nullptr, m0, n0, 6);
    } else {
        int q = (g / 3) * 8 + l8;                     // [0,1024)
        tile_coords(q, 1024, 16, m0, n0);
        gemm_core(As, Bs, DLT, WDT, 64, nullptr, nullptr, 0, DI,
                  nullptr, LD, nullptr, dtb, NA, m0, n0, 5);
    }
}

// single GEMM wrapper (G7): grid dim3(gn, gm)
template <int MODE>
__global__ __launch_bounds__(256, 4)
void k_gemm(const u16* __restrict__ A1, const u16* __restrict__ W1, int K1,
            const u16* __restrict__ A2, const u16* __restrict__ W2, int K2,
            int N, float* __restrict__ outf, u16* __restrict__ outb) {
    __shared__ u16 As[128 * 64];
    __shared__ u16 Bs[128 * 64];
    int bid = blockIdx.x + gridDim.x * blockIdx.y;
    int m0, n0;
    tile_coords(bid, gridDim.x * gridDim.y, gridDim.x, m0, n0);
    gemm_core(As, Bs, A1, W1, K1, A2, W2, K2, N,
              outf, outb, nullptr, nullptr, nullptr, m0, n0, MODE);
}

// ---------------------------------------------------------------------------
// cumsum over l (chunked): BXC bf16 -> (p1) chunk sums; (p23) folds carries,
// adds X3g in place: X3 = cumsum(BXC) + X3g
// thread layout: t = ((b*NCH + c)*DI + s); NCH*DI = 2^17
// ---------------------------------------------------------------------------
__global__ void k_cumsum_p1(const u16* __restrict__ Bx, float* __restrict__ aux) {
    int t = blockIdx.x * BDIM + threadIdx.x;
    int s = t & (DI - 1);
    int c = (t >> 11) & (NCH - 1);
    int b = t >> 17;
    const u16* p = Bx + ((size_t)(b * LSEQ + c * CLEN) * DI) + s;
    float sum = 0.f;
    for (int i = 0; i < CLEN; ++i) sum += bf2f(p[(size_t)i * DI]);
    aux[t] = sum;
}
__global__ void k_cumsum_p23(const u16* __restrict__ Bx, const float* __restrict__ aux,
                             u16* x3) {                 // read X3g, write X3 in place
    int t = blockIdx.x * BDIM + threadIdx.x;
    int s = t & (DI - 1);
    int c = (t >> 11) & (NCH - 1);
    int b = t >> 17;
    float run = 0.f;
    for (int j = 0; j < c; ++j) run += aux[(b * NCH + j) * DI + s];   // fold p2
    size_t base = ((size_t)(b * LSEQ + c * CLEN) * DI) + s;
    for (int i = 0; i < CLEN; ++i) {
        size_t ix = base + (size_t)i * DI;
        run += bf2f(Bx[ix]);
        x3[ix] = f2bf(run + bf2f(x3[ix]));
    }
}

// ---------------------------------------------------------------------------
// selective scan (2-kernel): s_l = a_l * s_{l-1} + u_l with a = exp(logdec)
// p23 fuses carry fold + x4 = s + u*D_ss ; out = x4 * silu(z)
// ---------------------------------------------------------------------------
__global__ void k_scan_p1(const u16* __restrict__ ld_, const u16* __restrict__ u,
                          float* __restrict__ auxA, float* __restrict__ auxS) {
    int t = blockIdx.x * BDIM + threadIdx.x;
    int d = t & (DI - 1);
    int c = (t >> 11) & (NCH - 1);
    int b = t >> 17;
    size_t base = ((size_t)(b * LSEQ + c * CLEN) * DI) + d;
    float ap = 1.f, s = 0.f;
    for (int i = 0; i < CLEN; ++i) {
        size_t ix = base + (size_t)i * DI;
        float a = __expf(bf2f(ld_[ix]));
        s = fmaf(a, s, bf2f(u[ix]));
        ap *= a;
    }
    auxA[t] = ap; auxS[t] = s;
}
__global__ void k_scan_p23(const u16* __restrict__ ld_, const u16* __restrict__ u,
                           const float* __restrict__ auxA, const float* __restrict__ auxS,
                           const u16* __restrict__ z, const float* __restrict__ Dss,
                           u16* __restrict__ outb) {
    int t = blockIdx.x * BDIM + threadIdx.x;
    int d = t & (DI - 1);
    int c = (t >> 11) & (NCH - 1);
    int b = t >> 17;
    float s = 0.f;
    for (int j = 0; j < c; ++j) {                                    // fold p2
        int i = (b * NCH + j) * DI + d;
        s = fmaf(auxA[i], s, auxS[i]);
    }
    size_t base = ((size_t)(b * LSEQ + c * CLEN) * DI) + d;
    float dss = Dss[d];
    for (int i = 0; i < CLEN; ++i) {
        size_t ix = base + (size_t)i * DI;
        float a = __expf(bf2f(ld_[ix]));
        float uu = bf2f(u[ix]);
        s = fmaf(a, s, uu);
        float x4 = s + uu * dss;
        float zz = bf2f(z[ix]);
        outb[ix] = f2bf(x4 * siluf(zz));
    }
}

// ---------------------------------------------------------------------------
extern "C" void kernel_launch(void* const* d_in, const int* in_sizes, int n_in,
                              void* d_out, int out_size, void* d_ws, size_t ws_size,
                              hipStream_t stream) {
    const float* hs     = (const float*)d_in[0];
    const float* delta  = (const float*)d_in[1];
    const float* inproj = (const float*)d_in[2];
    const float* convw  = (const float*)d_in[3];
    const float* convb  = (const float*)d_in[4];
    const float* Areal  = (const float*)d_in[5];
    const float* Bw     = (const float*)d_in[6];
    const float* Cw     = (const float*)d_in[7];
    const float* Dw     = (const float*)d_in[8];
    const float* dtw    = (const float*)d_in[9];
    const float* dtb    = (const float*)d_in[10];
    const float* Alog   = (const float*)d_in[11];
    const float* Dss    = (const float*)d_in[12];
    const float* outw   = (const float*)d_in[13];
    float* out = (float*)d_out;

    // ---- liveness-overlaid workspace layout (~241 MB total) ----
    const size_t SZ_ACT = (size_t)M_ROWS * DI * 2;     // 32 MB
    char* p = (char*)d_ws;
    u16* ZB  = (u16*)p; p += SZ_ACT;                   // z: batch1 -> scan_p23
    u16* XB  = (u16*)p;                                // x: batch1 -> conv
    u16* X3  = XB;      p += SZ_ACT;                   // X3g: batch36 -> cumsum_p23 (in place) -> scans
    u16* XC  = (u16*)p;                                // conv out -> batch36
    u16* OUT = XC;      p += SZ_ACT;                   // scan_p23 out -> G7
    u16* BXC = (u16*)p; p += SZ_ACT;                   // batch36 out -> cumsum
    u16* WCBp= (u16*)p;                                // C·B·P^T (8MB)
    u16* WXp = WCBp + (size_t)DI * DI;                 // (I+D_w)@P^T, CONTIGUOUS after WCBp
                        p += SZ_ACT;                   // 32MB slot holds both (16MB used)
    u16* XH  = (u16*)p;                                // hs bf16 (dead after batch1)
    u16* LD  = XH;                                     // log-decay overlays XH+W1+WBb (32MB)
                        p += (size_t)M_ROWS * 1024 * 2;   // 16 MB
    u16* W1  = (u16*)p; p += (size_t)4096 * 1024 * 2;     // 8 MB
    u16* WBb = (u16*)p; p += (size_t)DI * DI * 2;         // 8 MB  bf16(B_w)
    u16* WC  = (u16*)p; p += (size_t)DI * DI * 2;         // 8 MB  bf16(C_w)
    u16* Pb  = (u16*)p; p += (size_t)DI * DI * 2;         // 8 MB  bf16(I+A_real)
    u16* Db  = (u16*)p; p += (size_t)DI * DI * 2;         // 8 MB  bf16(I+D_w)
    u16* PBt = (u16*)p; p += (size_t)DI * DI * 2;         // 8 MB  P @ B^T
    p += (size_t)DI * DI * 2;                             // (old WXp slot, unused)
    u16* WO  = (u16*)p; p += (size_t)1024 * DI * 2;       // 4 MB
    u16* WDT = (u16*)p; p += (size_t)DI * 64 * 2;
    u16* DLT = (u16*)p; p += (size_t)M_ROWS * 64 * 2;
    float* aux1 = (float*)p; p += (size_t)2 * NCH * DI * 4;   // 1 MB
    float* auxA = (float*)p; p += (size_t)2 * NCH * DI * 4;
    float* auxS = (float*)p; p += (size_t)2 * NCH * DI * 4;
    float* NA   = (float*)p; p += (size_t)DI * 4;             // -exp(A_log)

    // 1) all converts (incl. +I for Pb/Db, NA tail)
    k_cvt_all<<<31362, BDIM, 0, stream>>>(hs, inproj, Bw, Cw, outw, delta, dtw,
                                          Areal, Dw, Alog,
                                          XH, W1, WBb, WC, WO, DLT, WDT, Pb, Db, NA);
    // 2) pre1' (PBt) + pre2 (WXp) + G1(split)
    k_batch1<<<2560, BDIM, 0, stream>>>(XH, W1, WBb, Pb, Db, PBt, WXp, XB, ZB);
    // 3) pre3 (WCBp, 256 blocks) + conv + SiLU
    k_conv_pre3<<<256 + (M_ROWS * DI) / BDIM, BDIM, 0, stream>>>(
        XB, convw, convb, XC, PBt, WC, WCBp);
    // 4) G36 ([BXC|X3g] = XC@[WCBp;WXp]^T) + G6 (LD), group-of-8 interleave
    k_batch36<<<3072, BDIM, 0, stream>>>(XC, WCBp, DLT, WDT, dtb, NA, BXC, X3, LD);
    // 5) cumsum chunk sums
    k_cumsum_p1<<<(2 * NCH * DI) / BDIM, BDIM, 0, stream>>>(BXC, aux1);
    // 6) cumsum fold + add: X3 = cumsum(BXC) + X3g   (in place)
    k_cumsum_p23<<<(2 * NCH * DI) / BDIM, BDIM, 0, stream>>>(BXC, aux1, X3);
    // 7-8) selective scan + epilogue -> OUT (overlays dead XC)
    k_scan_p1<<<(2 * NCH * DI) / BDIM, BDIM, 0, stream>>>(LD, X3, auxA, auxS);
    k_scan_p23<<<(2 * NCH * DI) / BDIM, BDIM, 0, stream>>>(LD, X3, auxA, auxS,
                                                           ZB, Dss, OUT);
    // 9) G7: out = OUT @ out_proj^T (f32)
    k_gemm<2><<<dim3(8, 64), BDIM, 0, stream>>>(OUT, WO, DI, nullptr, nullptr, 0,
                                                1024, out, nullptr);
}

// Round 5
// 636.412 us; speedup vs baseline: 1.1000x; 1.0952x over previous
//
#include <hip/hip_runtime.h>
#include <cstdint>
#include <cstddef>

// ---------------------------------------------------------------------------
// Mamba3Block on MI355X. B=2, L=4096, D_MODEL=1024, D_INNER=D_STATE=2048.
// R11: chunked-n tile map. Per XCD: 8-m-tile stripe, n walked in chunks of 8
// n-tiles (n fastest within chunk). One B-chunk (4MB) L2 fill serves all
// co-resident m-rows; A-stripe chunk (4MB) read once per chunk. Fixes R10's
// 470MB fetch on batch36 (window covered only ~2 m-rows at gn=32 + G6
// dilution -> B re-fetched 4x).
// Kept: G3''+G45'' merged (mode-6 split store), group-of-8 G36/G6 interleave,
// cumsum-commute algebra, fast softplus + NA precompute. 9 dispatches.
// GEMM core: bf16 MFMA 16x16x32, 128x128 tile, BK=64, global_load_lds w16,
// XOR-swizzled LDS (conflicts = 0). Scans fp32, bf16 log-decay storage.
// ---------------------------------------------------------------------------

typedef unsigned short u16;                 // bf16 storage (bit pattern)
typedef __bf16 bf16x8 __attribute__((ext_vector_type(8)));
typedef float  f32x4  __attribute__((ext_vector_type(4)));

#define BDIM 256
#define M_ROWS 8192            // B*L
#define LSEQ   4096
#define DI     2048            // d_inner / d_state
#define NCH    64              // scan chunks
#define CLEN   64              // LSEQ / NCH

__device__ __forceinline__ float bf2f(u16 h) {
    return __uint_as_float(((unsigned int)h) << 16);
}
__device__ __forceinline__ u16 f2bf(float f) {
    unsigned int u = __float_as_uint(f);
    u = u + 0x7fffu + ((u >> 16) & 1u);     // RNE
    return (u16)(u >> 16);
}
__device__ __forceinline__ float siluf(float v) { return v / (1.0f + __expf(-v)); }

__device__ __forceinline__ void load16_to_lds(const u16* g, u16* l) {
    __builtin_amdgcn_global_load_lds((const __attribute__((address_space(1))) void*)g,
                                     (__attribute__((address_space(3))) void*)l,
                                     16, 0, 0);
}

// ---------------------------------------------------------------------------
// fused f32 -> bf16 convert of ALL inputs (1 launch), incl. +I diag segments,
// plus tail segment: NA[d] = -exp(A_log[d]) (f32, 2048 elems).
// ---------------------------------------------------------------------------
__global__ void k_cvt_all(const float* __restrict__ hs, const float* __restrict__ inproj,
                          const float* __restrict__ Bw, const float* __restrict__ Cw,
                          const float* __restrict__ outw, const float* __restrict__ delta,
                          const float* __restrict__ dtw, const float* __restrict__ Areal,
                          const float* __restrict__ Dw, const float* __restrict__ Alog,
                          u16* __restrict__ XH, u16* __restrict__ W1, u16* __restrict__ WBb,
                          u16* __restrict__ WC, u16* __restrict__ WO, u16* __restrict__ DLT,
                          u16* __restrict__ WDT, u16* __restrict__ Pb, u16* __restrict__ Db,
                          float* __restrict__ NA) {
    long i = (long)(blockIdx.x * BDIM + threadIdx.x) * 4;
    if (i >= 32112640L) {                       // NA tail: 2048 f32
        long j = i - 32112640L;
        if (j < 2048) {
            float4 v = *reinterpret_cast<const float4*>(Alog + j);
            float4 o = {-__expf(v.x), -__expf(v.y), -__expf(v.z), -__expf(v.w)};
            *reinterpret_cast<float4*>(NA + j) = o;
        }
        return;
    }
    const float* src; u16* dst; long off; bool diag = false;
    if      (i <  8388608L) { src = hs;     dst = XH;  off = 0L; }
    else if (i < 12582912L) { src = inproj; dst = W1;  off = 8388608L; }
    else if (i < 16777216L) { src = Bw;     dst = WBb; off = 12582912L; }
    else if (i < 20971520L) { src = Cw;     dst = WC;  off = 16777216L; }
    else if (i < 23068672L) { src = outw;   dst = WO;  off = 20971520L; }
    else if (i < 23592960L) { src = delta;  dst = DLT; off = 23068672L; }
    else if (i < 23724032L) { src = dtw;    dst = WDT; off = 23592960L; }
    else if (i < 27918336L) { src = Areal;  dst = Pb;  off = 23724032L; diag = true; }
    else                    { src = Dw;     dst = Db;  off = 27918336L; diag = true; }
    long j = i - off;
    float4 v = *reinterpret_cast<const float4*>(src + j);
    if (diag) {
        int r = (int)(j >> 11), c = (int)(j & 2047);
        if (r >= c && r < c + 4) (&v.x)[r - c] += 1.0f;
    }
    ushort2 a = {f2bf(v.x), f2bf(v.y)};
    ushort2 b = {f2bf(v.z), f2bf(v.w)};
    *reinterpret_cast<ushort2*>(dst + j)     = a;
    *reinterpret_cast<ushort2*>(dst + j + 2) = b;
}

// ---------------------------------------------------------------------------
// GEMM tile core: C_tile = A1*W1^T (+ A2*W2^T), bf16 in, f32 acc.
// LDS XOR-swizzle (r,c) -> r*64 + (c ^ ((r&7)*8)); staging = global_load_lds.
// mode 0: store bf16[N-stride]; 2: store f32; 5: log-decay bf16 (bias2 = NA,
// premultiplied -exp(Alog), fast softplus); 6: split store; 8: transposed store
// ---------------------------------------------------------------------------
__device__ __forceinline__ void gemm_core(
    u16* As, u16* Bs,
    const u16* __restrict__ A1, const u16* __restrict__ W1, int K1,
    const u16* __restrict__ A2, const u16* __restrict__ W2, int K2,
    int N, float* __restrict__ outf, u16* __restrict__ outb, u16* __restrict__ outb2,
    const float* __restrict__ bias1, const float* __restrict__ bias2,
    int m0, int n0, int mode) {
    const int tid  = threadIdx.x;
    const int wave = tid >> 6;
    const int lane = tid & 63;
    const int wm = (wave >> 1) * 64;
    const int wn = (wave & 1) * 64;
    const int lr = lane & 15;
    const int lq = lane >> 4;
    const int stg_row = lane >> 3;
    const int stg_col = (((lane & 7) ^ (lane >> 3)) << 3);

    f32x4 acc[4][4] = {};

    const int nt1 = K1 >> 6;
    const int nt2 = K2 >> 6;
    const int ntot = nt1 + nt2;

    for (int kt = 0; kt < ntot; ++kt) {
        const u16* Ap; const u16* Wp; int ld, k0;
        if (kt < nt1) { Ap = A1; Wp = W1; ld = K1; k0 = kt << 6; }
        else          { Ap = A2; Wp = W2; ld = K2; k0 = (kt - nt1) << 6; }
        #pragma unroll
        for (int i = 0; i < 4; ++i) {
            int chunk = wave * 4 + i;                 // wave-uniform
            int r = chunk * 8 + stg_row;
            load16_to_lds(Ap + (size_t)(m0 + r) * ld + (k0 + stg_col), As + chunk * 512);
            load16_to_lds(Wp + (size_t)(n0 + r) * ld + (k0 + stg_col), Bs + chunk * 512);
        }
        __syncthreads();
        #pragma unroll
        for (int kk = 0; kk < 64; kk += 32) {
            bf16x8 af[4], bfr[4];
            #pragma unroll
            for (int i = 0; i < 4; ++i) {
                int R = wm + i * 16 + lr;
                af[i] = *reinterpret_cast<const bf16x8*>(
                    &As[R * 64 + ((kk + lq * 8) ^ ((R & 7) << 3))]);
            }
            #pragma unroll
            for (int i = 0; i < 4; ++i) {
                int R = wn + i * 16 + lr;
                bfr[i] = *reinterpret_cast<const bf16x8*>(
                    &Bs[R * 64 + ((kk + lq * 8) ^ ((R & 7) << 3))]);
            }
            #pragma unroll
            for (int mi = 0; mi < 4; ++mi)
                #pragma unroll
                for (int ni = 0; ni < 4; ++ni)
                    acc[mi][ni] = __builtin_amdgcn_mfma_f32_16x16x32_bf16(
                        af[mi], bfr[ni], acc[mi][ni], 0, 0, 0);
        }
        __syncthreads();
    }

    if (mode == 8) {                      // transposed store (square 2048 out)
        #pragma unroll
        for (int mi = 0; mi < 4; ++mi) {
            #pragma unroll
            for (int ni = 0; ni < 4; ++ni) {
                int row = m0 + wm + mi * 16 + lq * 4;
                int col = n0 + wn + ni * 16 + lr;
                ushort4 v;
                v.x = f2bf(acc[mi][ni][0]); v.y = f2bf(acc[mi][ni][1]);
                v.z = f2bf(acc[mi][ni][2]); v.w = f2bf(acc[mi][ni][3]);
                *reinterpret_cast<ushort4*>(outb + (size_t)col * 2048 + row) = v;
            }
        }
        return;
    }

    #pragma unroll
    for (int mi = 0; mi < 4; ++mi) {
        #pragma unroll
        for (int ni = 0; ni < 4; ++ni) {
            #pragma unroll
            for (int j = 0; j < 4; ++j) {
                int row = m0 + wm + mi * 16 + lq * 4 + j;
                int col = n0 + wn + ni * 16 + lr;
                float v = acc[mi][ni][j];
                if (mode == 6) {
                    if (col < 2048) outb [(size_t)row * 2048 + col]        = f2bf(v);
                    else            outb2[(size_t)row * 2048 + col - 2048] = f2bf(v);
                } else if (mode == 5) {
                    float dlt = v + bias1[col];
                    float sp  = (dlt > 15.f) ? dlt : __logf(1.f + __expf(dlt));
                    outb[(size_t)row * N + col] = f2bf(bias2[col] * sp);
                } else if (mode == 2) {
                    outf[(size_t)row * N + col] = v;
                } else {
                    outb[(size_t)row * N + col] = f2bf(v);
                }
            }
        }
    }
}

// Chunked-n M-stripe-per-XCD tile map: XCD (q&7) owns SM = T/(8*gn) m-tiles.
// n walked in chunks of CH=min(gn,8) n-tiles, n FASTEST within a chunk, m
// next, chunk outer. B-chunk (CH tiles) L2-fill is shared by the co-resident
// m-rows; A-stripe chunk read once per chunk.
__device__ __forceinline__ void tile_coords(int q, int T, int gn, int& m0, int& n0) {
    int xcd  = q & 7;
    int loc  = q >> 3;
    int SM   = (T >> 3) / gn;            // m-tiles per XCD stripe
    int CH   = gn < 8 ? gn : 8;          // n-chunk width
    int span = SM * CH;
    int chunk = loc / span;
    int rem   = loc - chunk * span;
    int ml    = rem / CH;
    int nl    = rem - ml * CH;
    m0 = (xcd * SM + ml) * 128;
    n0 = (chunk * CH + nl) * 128;
}

// batch1: [0,256) pre1' PBt = Pb@WBb^T = P@B^T | [256,512) pre2 WXp=Db@Pb^T |
//         [512,2560) G1 split: XZ = XH @ W1^T (N=4096) -> XB / ZB
__global__ __launch_bounds__(256, 4)
void k_batch1(const u16* __restrict__ XH, const u16* __restrict__ W1,
              const u16* __restrict__ WBb, const u16* __restrict__ Pb,
              const u16* __restrict__ Db,
              u16* __restrict__ PBt, u16* __restrict__ WXp,
              u16* __restrict__ XB, u16* __restrict__ ZB) {
    __shared__ u16 As[128 * 64];
    __shared__ u16 Bs[128 * 64];
    int bid = blockIdx.x;
    int m0, n0;
    if (bid < 256) {
        tile_coords(bid, 256, 16, m0, n0);
        gemm_core(As, Bs, Pb, WBb, DI, nullptr, nullptr, 0, DI,
                  nullptr, PBt, nullptr, nullptr, nullptr, m0, n0, 0);
    } else if (bid < 512) {
        tile_coords(bid - 256, 256, 16, m0, n0);
        gemm_core(As, Bs, Db, Pb, DI, nullptr, nullptr, 0, DI,
                  nullptr, WXp, nullptr, nullptr, nullptr, m0, n0, 0);
    } else {
        tile_coords(bid - 512, 2048, 32, m0, n0);
        gemm_core(As, Bs, XH, W1, 1024, nullptr, nullptr, 0, 4096,
                  nullptr, XB, ZB, nullptr, nullptr, m0, n0, 6);
    }
}

// conv+pre3: [0,256) pre3 WCBp = (PBt@WC^T)^T = C·B·P^T (mode 8) |
//            [256,...) depthwise causal conv (k=4) + bias + SiLU
__global__ __launch_bounds__(256, 4)
void k_conv_pre3(const u16* __restrict__ x, const float* __restrict__ w,
                 const float* __restrict__ b, u16* __restrict__ out,
                 const u16* __restrict__ PBt, const u16* __restrict__ WC,
                 u16* __restrict__ WCBp) {
    __shared__ u16 As[128 * 64];
    __shared__ u16 Bs[128 * 64];
    if (blockIdx.x < 256) {
        int m0, n0;
        tile_coords(blockIdx.x, 256, 16, m0, n0);
        gemm_core(As, Bs, PBt, WC, DI, nullptr, nullptr, 0, DI,
                  nullptr, WCBp, nullptr, nullptr, nullptr, m0, n0, 8);
        return;
    }
    int idx = (blockIdx.x - 256) * BDIM + threadIdx.x;   // over M_ROWS*DI
    int d  = idx & (DI - 1);
    int bl = idx >> 11;
    int l  = bl & (LSEQ - 1);
    float4 wv = *reinterpret_cast<const float4*>(w + d * 4);
    float wj[4] = {wv.x, wv.y, wv.z, wv.w};
    float acc = b[d];
    #pragma unroll
    for (int j = 0; j < 4; ++j) {
        int ll = l - 3 + j;
        if (ll >= 0) acc += wj[j] * bf2f(x[(size_t)(bl - 3 + j) * DI + d]);
    }
    out[idx] = f2bf(siluf(acc));
}

// batch36: merged G36 (2048 tiles) + G6 (1024 tiles), interleaved in groups
// of 8 blocks (pattern G36,G36,G6 repeating) so BOTH types cover all 8 XCDs
// and G6's VALU/store hides under G36's MFMA.
//  G36: [BXC | X3g] = XC @ [WCBp ; WXp]^T   (N=4096, mode-6 split store)
//  G6 : LD = logdecay(DLT@WDT^T)            (mode 5)
__global__ __launch_bounds__(256, 4)
void k_batch36(const u16* __restrict__ XC, const u16* __restrict__ WCB2,
               const u16* __restrict__ DLT, const u16* __restrict__ WDT,
               const float* __restrict__ dtb, const float* __restrict__ NA,
               u16* __restrict__ BXC, u16* __restrict__ X3, u16* __restrict__ LD) {
    __shared__ u16 As[128 * 64];
    __shared__ u16 Bs[128 * 64];
    int bid = blockIdx.x;
    int g   = bid >> 3;
    int l8  = bid & 7;
    int t3  = g % 3;                       // 0,1 -> G36 ; 2 -> G6
    int m0, n0;
    if (t3 < 2) {
        int q = ((g / 3) * 2 + t3) * 8 + l8;          // [0,2048)
        tile_coords(q, 2048, 32, m0, n0);
        gemm_core(As, Bs, XC, WCB2, DI, nullptr, nullptr, 0, 4096,
                  nullptr, BXC, X3, nullptr, nullptr, m0, n0, 6);
    } else {
        int q = (g / 3) * 8 + l8;                     // [0,1024)
        tile_coords(q, 1024, 16, m0, n0);
        gemm_core(As, Bs, DLT, WDT, 64, nullptr, nullptr, 0, DI,
                  nullptr, LD, nullptr, dtb, NA, m0, n0, 5);
    }
}

// single GEMM wrapper (G7): grid dim3(gn, gm)
template <int MODE>
__global__ __launch_bounds__(256, 4)
void k_gemm(const u16* __restrict__ A1, const u16* __restrict__ W1, int K1,
            const u16* __restrict__ A2, const u16* __restrict__ W2, int K2,
            int N, float* __restrict__ outf, u16* __restrict__ outb) {
    __shared__ u16 As[128 * 64];
    __shared__ u16 Bs[128 * 64];
    int bid = blockIdx.x + gridDim.x * blockIdx.y;
    int m0, n0;
    tile_coords(bid, gridDim.x * gridDim.y, gridDim.x, m0, n0);
    gemm_core(As, Bs, A1, W1, K1, A2, W2, K2, N,
              outf, outb, nullptr, nullptr, nullptr, m0, n0, MODE);
}

// ---------------------------------------------------------------------------
// cumsum over l (chunked): BXC bf16 -> (p1) chunk sums; (p23) folds carries,
// adds X3g in place: X3 = cumsum(BXC) + X3g
// thread layout: t = ((b*NCH + c)*DI + s); NCH*DI = 2^17
// ---------------------------------------------------------------------------
__global__ void k_cumsum_p1(const u16* __restrict__ Bx, float* __restrict__ aux) {
    int t = blockIdx.x * BDIM + threadIdx.x;
    int s = t & (DI - 1);
    int c = (t >> 11) & (NCH - 1);
    int b = t >> 17;
    const u16* p = Bx + ((size_t)(b * LSEQ + c * CLEN) * DI) + s;
    float sum = 0.f;
    for (int i = 0; i < CLEN; ++i) sum += bf2f(p[(size_t)i * DI]);
    aux[t] = sum;
}
__global__ void k_cumsum_p23(const u16* __restrict__ Bx, const float* __restrict__ aux,
                             u16* x3) {                 // read X3g, write X3 in place
    int t = blockIdx.x * BDIM + threadIdx.x;
    int s = t & (DI - 1);
    int c = (t >> 11) & (NCH - 1);
    int b = t >> 17;
    float run = 0.f;
    for (int j = 0; j < c; ++j) run += aux[(b * NCH + j) * DI + s];   // fold p2
    size_t base = ((size_t)(b * LSEQ + c * CLEN) * DI) + s;
    for (int i = 0; i < CLEN; ++i) {
        size_t ix = base + (size_t)i * DI;
        run += bf2f(Bx[ix]);
        x3[ix] = f2bf(run + bf2f(x3[ix]));
    }
}

// ---------------------------------------------------------------------------
// selective scan (2-kernel): s_l = a_l * s_{l-1} + u_l with a = exp(logdec)
// p23 fuses carry fold + x4 = s + u*D_ss ; out = x4 * silu(z)
// ---------------------------------------------------------------------------
__global__ void k_scan_p1(const u16* __restrict__ ld_, const u16* __restrict__ u,
                          float* __restrict__ auxA, float* __restrict__ auxS) {
    int t = blockIdx.x * BDIM + threadIdx.x;
    int d = t & (DI - 1);
    int c = (t >> 11) & (NCH - 1);
    int b = t >> 17;
    size_t base = ((size_t)(b * LSEQ + c * CLEN) * DI) + d;
    float ap = 1.f, s = 0.f;
    for (int i = 0; i < CLEN; ++i) {
        size_t ix = base + (size_t)i * DI;
        float a = __expf(bf2f(ld_[ix]));
        s = fmaf(a, s, bf2f(u[ix]));
        ap *= a;
    }
    auxA[t] = ap; auxS[t] = s;
}
__global__ void k_scan_p23(const u16* __restrict__ ld_, const u16* __restrict__ u,
                           const float* __restrict__ auxA, const float* __restrict__ auxS,
                           const u16* __restrict__ z, const float* __restrict__ Dss,
                           u16* __restrict__ outb) {
    int t = blockIdx.x * BDIM + threadIdx.x;
    int d = t & (DI - 1);
    int c = (t >> 11) & (NCH - 1);
    int b = t >> 17;
    float s = 0.f;
    for (int j = 0; j < c; ++j) {                                    // fold p2
        int i = (b * NCH + j) * DI + d;
        s = fmaf(auxA[i], s, auxS[i]);
    }
    size_t base = ((size_t)(b * LSEQ + c * CLEN) * DI) + d;
    float dss = Dss[d];
    for (int i = 0; i < CLEN; ++i) {
        size_t ix = base + (size_t)i * DI;
        float a = __expf(bf2f(ld_[ix]));
        float uu = bf2f(u[ix]);
        s = fmaf(a, s, uu);
        float x4 = s + uu * dss;
        float zz = bf2f(z[ix]);
        outb[ix] = f2bf(x4 * siluf(zz));
    }
}

// ---------------------------------------------------------------------------
extern "C" void kernel_launch(void* const* d_in, const int* in_sizes, int n_in,
                              void* d_out, int out_size, void* d_ws, size_t ws_size,
                              hipStream_t stream) {
    const float* hs     = (const float*)d_in[0];
    const float* delta  = (const float*)d_in[1];
    const float* inproj = (const float*)d_in[2];
    const float* convw  = (const float*)d_in[3];
    const float* convb  = (const float*)d_in[4];
    const float* Areal  = (const float*)d_in[5];
    const float* Bw     = (const float*)d_in[6];
    const float* Cw     = (const float*)d_in[7];
    const float* Dw     = (const float*)d_in[8];
    const float* dtw    = (const float*)d_in[9];
    const float* dtb    = (const float*)d_in[10];
    const float* Alog   = (const float*)d_in[11];
    const float* Dss    = (const float*)d_in[12];
    const float* outw   = (const float*)d_in[13];
    float* out = (float*)d_out;

    // ---- liveness-overlaid workspace layout (~241 MB total) ----
    const size_t SZ_ACT = (size_t)M_ROWS * DI * 2;     // 32 MB
    char* p = (char*)d_ws;
    u16* ZB  = (u16*)p; p += SZ_ACT;                   // z: batch1 -> scan_p23
    u16* XB  = (u16*)p;                                // x: batch1 -> conv
    u16* X3  = XB;      p += SZ_ACT;                   // X3g: batch36 -> cumsum_p23 (in place) -> scans
    u16* XC  = (u16*)p;                                // conv out -> batch36
    u16* OUT = XC;      p += SZ_ACT;                   // scan_p23 out -> G7
    u16* BXC = (u16*)p; p += SZ_ACT;                   // batch36 out -> cumsum
    u16* WCBp= (u16*)p;                                // C·B·P^T (8MB)
    u16* WXp = WCBp + (size_t)DI * DI;                 // (I+D_w)@P^T, CONTIGUOUS after WCBp
                        p += SZ_ACT;                   // 32MB slot holds both (16MB used)
    u16* XH  = (u16*)p;                                // hs bf16 (dead after batch1)
    u16* LD  = XH;                                     // log-decay overlays XH+W1+WBb (32MB)
                        p += (size_t)M_ROWS * 1024 * 2;   // 16 MB
    u16* W1  = (u16*)p; p += (size_t)4096 * 1024 * 2;     // 8 MB
    u16* WBb = (u16*)p; p += (size_t)DI * DI * 2;         // 8 MB  bf16(B_w)
    u16* WC  = (u16*)p; p += (size_t)DI * DI * 2;         // 8 MB  bf16(C_w)
    u16* Pb  = (u16*)p; p += (size_t)DI * DI * 2;         // 8 MB  bf16(I+A_real)
    u16* Db  = (u16*)p; p += (size_t)DI * DI * 2;         // 8 MB  bf16(I+D_w)
    u16* PBt = (u16*)p; p += (size_t)DI * DI * 2;         // 8 MB  P @ B^T
    p += (size_t)DI * DI * 2;                             // (old WXp slot, unused)
    u16* WO  = (u16*)p; p += (size_t)1024 * DI * 2;       // 4 MB
    u16* WDT = (u16*)p; p += (size_t)DI * 64 * 2;
    u16* DLT = (u16*)p; p += (size_t)M_ROWS * 64 * 2;
    float* aux1 = (float*)p; p += (size_t)2 * NCH * DI * 4;   // 1 MB
    float* auxA = (float*)p; p += (size_t)2 * NCH * DI * 4;
    float* auxS = (float*)p; p += (size_t)2 * NCH * DI * 4;
    float* NA   = (float*)p; p += (size_t)DI * 4;             // -exp(A_log)

    // 1) all converts (incl. +I for Pb/Db, NA tail)
    k_cvt_all<<<31362, BDIM, 0, stream>>>(hs, inproj, Bw, Cw, outw, delta, dtw,
                                          Areal, Dw, Alog,
                                          XH, W1, WBb, WC, WO, DLT, WDT, Pb, Db, NA);
    // 2) pre1' (PBt) + pre2 (WXp) + G1(split)
    k_batch1<<<2560, BDIM, 0, stream>>>(XH, W1, WBb, Pb, Db, PBt, WXp, XB, ZB);
    // 3) pre3 (WCBp, 256 blocks) + conv + SiLU
    k_conv_pre3<<<256 + (M_ROWS * DI) / BDIM, BDIM, 0, stream>>>(
        XB, convw, convb, XC, PBt, WC, WCBp);
    // 4) G36 ([BXC|X3g] = XC@[WCBp;WXp]^T) + G6 (LD), group-of-8 interleave
    k_batch36<<<3072, BDIM, 0, stream>>>(XC, WCBp, DLT, WDT, dtb, NA, BXC, X3, LD);
    // 5) cumsum chunk sums
    k_cumsum_p1<<<(2 * NCH * DI) / BDIM, BDIM, 0, stream>>>(BXC, aux1);
    // 6) cumsum fold + add: X3 = cumsum(BXC) + X3g   (in place)
    k_cumsum_p23<<<(2 * NCH * DI) / BDIM, BDIM, 0, stream>>>(BXC, aux1, X3);
    // 7-8) selective scan + epilogue -> OUT (overlays dead XC)
    k_scan_p1<<<(2 * NCH * DI) / BDIM, BDIM, 0, stream>>>(LD, X3, auxA, auxS);
    k_scan_p23<<<(2 * NCH * DI) / BDIM, BDIM, 0, stream>>>(LD, X3, auxA, auxS,
                                                           ZB, Dss, OUT);
    // 9) G7: out = OUT @ out_proj^T (f32)
    k_gemm<2><<<dim3(8, 64), BDIM, 0, stream>>>(OUT, WO, DI, nullptr, nullptr, 0,
                                                1024, out, nullptr);
}